// Round 5
// baseline (2563.498 us; speedup 1.0000x reference)
//
#include <hip/hip_runtime.h>

// T=256, B=512, D=256, H=512, 4H=2048. Persistent 256 blocks x 256 threads.
// Block (mt=bid&7, nt=bid>>3): batch rows mt*64..+63, h-cols nt*16..+15.
//
// W-in-VGPR swapped-operand MFMA (round-5, spill-immune variant):
//   Wave w owns gates {2*(w&1), 2*(w&1)+1} x 16 h-cols as MFMA A-operand
//   (48 frags = 192 VGPRs, loaded once). Activations are the B-operand,
//   loaded straight from global (x f32 + cvt; h f16 history, plain loads).
//   ZERO LDS reads in the GEMM (proven kernel streamed 384 ds_read_b128 /
//   block / step). Gates recombined via single-buffer LDS exchange with two
//   barriers per step (write -> bar -> read -> bar): trivially race-free.
// Safety rules this round: ALL waits are s_waitcnt vmcnt(0) (full drain) so
// compiler spill traffic can never break a counted wait; peak live VGPRs
// ~390 (N-tiles sequential, shared hf[16]).
// Sync machinery (per-wave flags sc0 sc1, polls, h write-once history with
// plain consumer loads), attention, MLP epilogue: verbatim from the proven
// 1609us kernel.

typedef _Float16 f16x8 __attribute__((ext_vector_type(8)));
typedef short    s16x8 __attribute__((ext_vector_type(8)));
typedef float    f32x4 __attribute__((ext_vector_type(4)));

union F16U { f16x8 v; _Float16 e[8]; };

__device__ __forceinline__ float h2f(unsigned short b) {
    return (float)__builtin_bit_cast(_Float16, b);
}
__device__ __forceinline__ unsigned short f2h(float f) {
    return __builtin_bit_cast(unsigned short, (_Float16)f);
}
__device__ __forceinline__ float sigf(float x) { return 1.0f / (1.0f + __expf(-x)); }
__device__ __forceinline__ float tanh_(float x) {
    float e = __expf(-2.0f * fabsf(x));
    float r = (1.0f - e) / (1.0f + e);
    return x < 0.0f ? -r : r;
}
__device__ __forceinline__ unsigned umin_(unsigned a, unsigned b) { return a < b ? a : b; }

__device__ __forceinline__ f16x8 loadA32(const float* p) {
    float4 a = *(const float4*)p, b = *(const float4*)(p + 4);
    F16U r;
    r.e[0]=(_Float16)a.x; r.e[1]=(_Float16)a.y; r.e[2]=(_Float16)a.z; r.e[3]=(_Float16)a.w;
    r.e[4]=(_Float16)b.x; r.e[5]=(_Float16)b.y; r.e[6]=(_Float16)b.z; r.e[7]=(_Float16)b.w;
    return r.v;
}

#define MFMA16(a, b, c) __builtin_amdgcn_mfma_f32_16x16x32_f16((a), (b), (c), 0, 0, 0)

// Issue 16 x-loads (8 kc x 2 halves) for one 16-row tile (fire-and-forget).
__device__ __forceinline__ void issue_x(const float* x_t, int arow, int lq, float4* xpf) {
    const float* xb = x_t + (size_t)arow * 256 + lq * 8;
#pragma unroll
    for (int i = 0; i < 8; ++i) {
        asm volatile("global_load_dwordx4 %0, %1, off offset:%c2"
                     : "=v"(xpf[2 * i]) : "v"(xb), "i"(i * 128));
        asm volatile("global_load_dwordx4 %0, %1, off offset:%c2"
                     : "=v"(xpf[2 * i + 1]) : "v"(xb), "i"(i * 128 + 16));
    }
}

__device__ __forceinline__ void cvt8(const float4* xpf, f16x8* xf) {
#pragma unroll
    for (int kc = 0; kc < 8; ++kc) {
        float4 a = xpf[2 * kc], b = xpf[2 * kc + 1];
        F16U r;
        r.e[0]=(_Float16)a.x; r.e[1]=(_Float16)a.y; r.e[2]=(_Float16)a.z; r.e[3]=(_Float16)a.w;
        r.e[4]=(_Float16)b.x; r.e[5]=(_Float16)b.y; r.e[6]=(_Float16)b.z; r.e[7]=(_Float16)b.w;
        xf[kc] = r.v;
    }
}

// Poll group's 32 producer blocks (4 wave-flags each). sc0 sc1 REQUIRED.
__device__ __forceinline__ void wait_flags(const uint4* fbase, int l, unsigned target) {
    if (l < 32) {
        const uint4* p = fbase + l;
        unsigned m;
        do {
            uint4 v;
            asm volatile("global_load_dwordx4 %0, %1, off sc0 sc1" : "=v"(v) : "v"(p));
            asm volatile("s_waitcnt vmcnt(0)" ::: "memory");
            m = umin_(umin_(v.x, v.y), umin_(v.z, v.w));
        } while (m < target);
    }
    __builtin_amdgcn_sched_barrier(0);
}

__device__ __forceinline__ void attn_apply(uint4 hd, uint2 hc, const float* wv8,
    float s_bias, float& m_r, float& l_r, float ctx[4])
{
    float p = h2f((unsigned short)(hd.x & 0xffffu)) * wv8[0]
            + h2f((unsigned short)(hd.x >> 16))     * wv8[1]
            + h2f((unsigned short)(hd.y & 0xffffu)) * wv8[2]
            + h2f((unsigned short)(hd.y >> 16))     * wv8[3]
            + h2f((unsigned short)(hd.z & 0xffffu)) * wv8[4]
            + h2f((unsigned short)(hd.z >> 16))     * wv8[5]
            + h2f((unsigned short)(hd.w & 0xffffu)) * wv8[6]
            + h2f((unsigned short)(hd.w >> 16))     * wv8[7];
#pragma unroll
    for (int off = 32; off > 0; off >>= 1) p += __shfl_xor(p, off);
    float s = p + s_bias;
    float m_new = fmaxf(m_r, s);
    float scale = __expf(m_r - m_new);   // exp(-inf)=0 on first update
    float pr    = __expf(s - m_new);
    ctx[0] = ctx[0] * scale + pr * h2f((unsigned short)(hc.x & 0xffffu));
    ctx[1] = ctx[1] * scale + pr * h2f((unsigned short)(hc.x >> 16));
    ctx[2] = ctx[2] * scale + pr * h2f((unsigned short)(hc.y & 0xffffu));
    ctx[3] = ctx[3] * scale + pr * h2f((unsigned short)(hc.y >> 16));
    l_r = l_r * scale + pr;
    m_r = m_new;
}

// LDS: gate exchange 64 rows x 68 floats = 17408B + bsum + MLP scratch.
#define GSTRIDE 68
#define SMEM_BYTES 24576

__global__ __launch_bounds__(256, 1) void lstm_wreg(
    const float* __restrict__ xg,
    const float* __restrict__ hinit, const float* __restrict__ cinit,
    const float* __restrict__ W_ih, const float* __restrict__ W_hh,
    const float* __restrict__ b_ih, const float* __restrict__ b_hh,
    const float* __restrict__ attn_w, const float* __restrict__ attn_b,
    const float* __restrict__ W1, const float* __restrict__ b1,
    const float* __restrict__ W2, const float* __restrict__ b2,
    const float* __restrict__ W3, const float* __restrict__ b3,
    const float* __restrict__ W4, const float* __restrict__ b4,
    float* __restrict__ out,
    unsigned short* __restrict__ hs, unsigned* __restrict__ flags)
{
    extern __shared__ char smem[];
    float* gbuf = (float*)smem;                  // 4352 floats
    float* bsum = (float*)(smem + 17408);        // 64
    float* xmlp = (float*)(smem + 17664);        // 1024
    float* x1s  = xmlp + 1024;                   // 128
    float* x2s  = x1s + 128;                     // 128
    float* x3s  = x2s + 128;                     // 64

    const int tid = threadIdx.x, bid = blockIdx.x;
    const int mt = bid & 7, nt = bid >> 3;
    const int hc0 = nt * 16;
    const int w = tid >> 6, l = tid & 63;
    const int lj = l & 15, lq = l >> 4;
    const int gA = (w & 1) * 2;        // this wave's gates: gA, gA+1
    const int rh = (w >> 1) * 32;      // this wave's block-local rows rh..rh+31

    if (tid < 64) {
        int gr = (tid >> 4) * 512 + hc0 + (tid & 15);
        bsum[tid] = b_ih[gr] + b_hh[gr];
    }

    // ---- W A-fragments into registers (one-time). Lane lj = h-col row. ----
    f16x8 WA0[24], WA1[24];
    {
        int wr0 = gA * 512 + hc0 + lj;
        int wr1 = (gA + 1) * 512 + hc0 + lj;
        const float* i0 = W_ih + (size_t)wr0 * 256 + lq * 8;
        const float* h0 = W_hh + (size_t)wr0 * 512 + lq * 8;
        const float* i1 = W_ih + (size_t)wr1 * 256 + lq * 8;
        const float* h1 = W_hh + (size_t)wr1 * 512 + lq * 8;
#pragma unroll
        for (int kc = 0; kc < 8; ++kc) {
            WA0[kc] = loadA32(i0 + kc * 32);
            WA1[kc] = loadA32(i1 + kc * 32);
        }
#pragma unroll
        for (int kc = 8; kc < 24; ++kc) {
            WA0[kc] = loadA32(h0 + (kc - 8) * 32);
            WA1[kc] = loadA32(h1 + (kc - 8) * 32);
        }
    }
    __syncthreads();   // bsum ready

    // ---- pointwise mapping: thread owns (rows rowq*4..+3, col hcol) ----
    const int hcol = tid & 15, rowq = tid >> 4;
    float creg[4];
#pragma unroll
    for (int rr = 0; rr < 4; ++rr)
        creg[rr] = cinit[(size_t)(mt * 64 + rowq * 4 + rr) * 512 + hc0 + hcol];
    float bsI = bsum[hcol], bsF = bsum[16 + hcol], bsG = bsum[32 + hcol], bsO = bsum[48 + hcol];

    // ---- attention state (verbatim from proven kernel) ----
    float m_r = -__builtin_inff(), l_r = 0.f;
    float ctx[4] = {0.f, 0.f, 0.f, 0.f};
    uint4 hdot = {0, 0, 0, 0}; uint2 hctx = {0, 0};
    const int attr0 = mt * 64 + nt * 2;
    const int arow_at = attr0 + (w >> 1);
    const float s_bias = attn_b[0];
    float wv8[8];
    {
        float4 a = *(const float4*)(attn_w + l * 8);
        float4 b = *(const float4*)(attn_w + l * 8 + 4);
        wv8[0]=a.x; wv8[1]=a.y; wv8[2]=a.z; wv8[3]=a.w;
        wv8[4]=b.x; wv8[5]=b.y; wv8[6]=b.z; wv8[7]=b.w;
    }
    const size_t aoff_dot = (size_t)arow_at * 512 + l * 8;
    const size_t aoff_ctx = (size_t)arow_at * 512 + (w & 1) * 256 + l * 4;
    const uint4* fbase = (const uint4*)flags + mt * 32;
    unsigned* myflag = flags + (size_t)(mt * 32 + nt) * 4 + w;

    // B-operand (activation) row bases: lane lj = batch row
    const int brow0 = mt * 64 + rh + lj;       // N-tile 0
    const int brow1 = brow0 + 16;              // N-tile 1

    for (int t = 0; t < 256; ++t) {
        unsigned short* hb_cur = hs + (size_t)t * 262144;
        const unsigned short* hb_prev = hb_cur - 262144;
        const float* xt = xg + (size_t)t * 131072;

        // stage both x tiles; latency overlaps attn + flag wait
        float4 xpf0[16], xpf1[16];
        issue_x(xt, brow0, lq, xpf0);
        issue_x(xt, brow1, lq, xpf1);

        if (t >= 2) attn_apply(hdot, hctx, wv8, s_bias, m_r, l_r, ctx);
        if (t > 0) wait_flags(fbase, l, (unsigned)t);

        asm volatile("s_waitcnt vmcnt(0)" ::: "memory");   // x tiles arrived
        __builtin_amdgcn_sched_barrier(0);
        f16x8 xf0[8], xf1[8];
        cvt8(xpf0, xf0);
        cvt8(xpf1, xf1);

        f32x4 a00 = {0,0,0,0}, a10 = {0,0,0,0}, a01 = {0,0,0,0}, a11 = {0,0,0,0};
#pragma unroll
        for (int kc = 0; kc < 8; ++kc) {
            a00 = MFMA16(WA0[kc], xf0[kc], a00);
            a10 = MFMA16(WA1[kc], xf0[kc], a10);
            a01 = MFMA16(WA0[kc], xf1[kc], a01);
            a11 = MFMA16(WA1[kc], xf1[kc], a11);
        }

        if (t > 0) {
            // attn loads (plain; write-once history) + h tile 0
            asm volatile("global_load_dwordx4 %0, %1, off" : "=v"(hdot) : "v"(hb_prev + aoff_dot));
            asm volatile("global_load_dwordx2 %0, %1, off" : "=v"(hctx) : "v"(hb_prev + aoff_ctx));
            s16x8 hf[16];
            const unsigned short* hp0 = hb_prev + (size_t)brow0 * 512 + lq * 8;
#pragma unroll
            for (int i = 0; i < 16; ++i)
                asm volatile("global_load_dwordx4 %0, %1, off offset:%c2"
                             : "=v"(hf[i]) : "v"(hp0), "i"(i * 64));
            asm volatile("s_waitcnt vmcnt(0)" ::: "memory");
            __builtin_amdgcn_sched_barrier(0);
#pragma unroll
            for (int kc = 0; kc < 16; ++kc) {
                f16x8 b = __builtin_bit_cast(f16x8, hf[kc]);
                a00 = MFMA16(WA0[8 + kc], b, a00);
                a10 = MFMA16(WA1[8 + kc], b, a10);
            }
            // h tile 1 (reuse hf)
            const unsigned short* hp1 = hb_prev + (size_t)brow1 * 512 + lq * 8;
#pragma unroll
            for (int i = 0; i < 16; ++i)
                asm volatile("global_load_dwordx4 %0, %1, off offset:%c2"
                             : "=v"(hf[i]) : "v"(hp1), "i"(i * 64));
            asm volatile("s_waitcnt vmcnt(0)" ::: "memory");
            __builtin_amdgcn_sched_barrier(0);
#pragma unroll
            for (int kc = 0; kc < 16; ++kc) {
                f16x8 b = __builtin_bit_cast(f16x8, hf[kc]);
                a01 = MFMA16(WA0[8 + kc], b, a01);
                a11 = MFMA16(WA1[8 + kc], b, a11);
            }
        } else {
            // t=0: h from fp32 hinit (compiler-managed waits)
            const float* hb0p = hinit + (size_t)brow0 * 512 + lq * 8;
            const float* hb1p = hinit + (size_t)brow1 * 512 + lq * 8;
#pragma unroll
            for (int kc = 0; kc < 16; ++kc) {
                f16x8 b0 = loadA32(hb0p + kc * 32);
                f16x8 b1 = loadA32(hb1p + kc * 32);
                a00 = MFMA16(WA0[8 + kc], b0, a00);
                a10 = MFMA16(WA1[8 + kc], b0, a10);
                a01 = MFMA16(WA0[8 + kc], b1, a01);
                a11 = MFMA16(WA1[8 + kc], b1, a11);
            }
        }

        // ---- gate exchange (single buffer, write -> bar -> read) ----
        // a00[r] = gate gA,   h-col lq*4+r, batch row rh+lj     (D: col=lane&15=N,
        // a10[r] = gate gA+1, same tile;  a01/a11 = rows rh+16+lj.  row=lq*4+reg=M)
        {
            int r0 = (rh + lj) * GSTRIDE + gA * 17 + lq * 4;
            int r1 = (rh + 16 + lj) * GSTRIDE + gA * 17 + lq * 4;
#pragma unroll
            for (int r = 0; r < 4; ++r) {
                gbuf[r0 + r]      = a00[r];
                gbuf[r0 + 17 + r] = a10[r];
                gbuf[r1 + r]      = a01[r];
                gbuf[r1 + 17 + r] = a11[r];
            }
        }
        __syncthreads();

        // ---- pointwise: i,f,g,o -> c,h; h stores sc0 sc1 (write-through) ----
#pragma unroll
        for (int rr = 0; rr < 4; ++rr) {
            int row = rowq * 4 + rr;
            int base = row * GSTRIDE + hcol;
            float vi = gbuf[base]      + bsI;
            float vf = gbuf[base + 17] + bsF;
            float vg = gbuf[base + 34] + bsG;
            float vo = gbuf[base + 51] + bsO;
            float ii = sigf(vi), ff = sigf(vf), gt = tanh_(vg), oo = sigf(vo);
            float cn = ff * creg[rr] + ii * gt;
            creg[rr] = cn;
            float hv = oo * tanh_(cn);
            size_t off = (size_t)(mt * 64 + row) * 512 + hc0 + hcol;
            unsigned short hvs = f2h(hv);
            unsigned short* sp = hb_cur + off;
            asm volatile("global_store_short %0, %1, off sc0 sc1"
                         :: "v"(sp), "v"(hvs) : "memory");
            if (t == 255) out[512 + off] = hv;   // hT fp32
        }

        asm volatile("s_waitcnt vmcnt(0)" ::: "memory");   // drain h stores
        if (l == 0) {
            unsigned fv = (unsigned)(t + 1);
            asm volatile("global_store_dword %0, %1, off sc0 sc1"
                         :: "v"(myflag), "v"(fv) : "memory");
        }
        __syncthreads();   // protect gbuf reuse next iteration
    }

    // post-loop: attention for h_254 (regs loaded at t=255), then h_255
    attn_apply(hdot, hctx, wv8, s_bias, m_r, l_r, ctx);
    wait_flags(fbase, l, 256u);
    {
        const unsigned short* hlast = hs + (size_t)255 * 262144;
        asm volatile("global_load_dwordx4 %0, %1, off" : "=v"(hdot) : "v"(hlast + aoff_dot));
        asm volatile("global_load_dwordx2 %0, %1, off" : "=v"(hctx) : "v"(hlast + aoff_ctx));
        asm volatile("s_waitcnt vmcnt(0)" ::: "memory");
        __builtin_amdgcn_sched_barrier(0);
        attn_apply(hdot, hctx, wv8, s_bias, m_r, l_r, ctx);
    }

    // cT copyout (pointwise mapping)
#pragma unroll
    for (int rr = 0; rr < 4; ++rr)
        out[512 + 262144 + (size_t)(mt * 64 + rowq * 4 + rr) * 512 + hc0 + hcol] = creg[rr];

    // ---- fused output MLP for this block's 2 batch rows (verbatim) ----
    {
        float linv = 1.0f / l_r;
        int row = tid >> 7, coff = (tid & 127) * 4;   // == (w&1)*256 + l*4
#pragma unroll
        for (int i = 0; i < 4; ++i) xmlp[row * 512 + coff + i] = ctx[i] * linv;
    }
    __syncthreads();
    if (tid < 128) {
        int r = tid >> 6, f = tid & 63;
        const float* wp = W1 + (size_t)f * 512;
        const float* xp = xmlp + r * 512;
        float a = b1[f];
        for (int j = 0; j < 512; ++j) a = fmaf(xp[j], wp[j], a);
        x1s[r * 64 + f] = tanh_(a);
    }
    __syncthreads();
    if (tid < 128) {
        int r = tid >> 6, f = tid & 63;
        const float* wp = W2 + f * 64;
        const float* xp = x1s + r * 64;
        float a = b2[f];
        for (int j = 0; j < 64; ++j) a = fmaf(xp[j], wp[j], a);
        x2s[r * 64 + f] = tanh_(a);
    }
    __syncthreads();
    if (tid < 64) {
        int r = tid >> 5, f = tid & 31;
        const float* wp = W3 + f * 64;
        const float* xp = x2s + r * 64;
        float a = b3[f];
        for (int j = 0; j < 64; ++j) a = fmaf(xp[j], wp[j], a);
        x3s[r * 32 + f] = tanh_(a);
    }
    __syncthreads();
    if (tid < 2) {
        const float* xp = x3s + tid * 32;
        float a = b4[0];
        for (int j = 0; j < 32; ++j) a = fmaf(xp[j], W4[j], a);
        out[attr0 + tid] = a;
    }
}

extern "C" void kernel_launch(void* const* d_in, const int* in_sizes, int n_in,
                              void* d_out, int out_size, void* d_ws, size_t ws_size,
                              hipStream_t stream) {
    const float* xg     = (const float*)d_in[0];
    const float* hinit  = (const float*)d_in[1];
    const float* cinit  = (const float*)d_in[2];
    const float* W_ih   = (const float*)d_in[3];
    const float* W_hh   = (const float*)d_in[4];
    const float* b_ih   = (const float*)d_in[5];
    const float* b_hh   = (const float*)d_in[6];
    const float* attn_w = (const float*)d_in[7];
    const float* attn_b = (const float*)d_in[8];
    const float* W1 = (const float*)d_in[9],  *b1 = (const float*)d_in[10];
    const float* W2 = (const float*)d_in[11], *b2 = (const float*)d_in[12];
    const float* W3 = (const float*)d_in[13], *b3 = (const float*)d_in[14];
    const float* W4 = (const float*)d_in[15], *b4 = (const float*)d_in[16];

    const size_t HS_BYTES = 134217728ull;   // 256 x 512 x 512 f16 history
    unsigned short* hs = (unsigned short*)d_ws;
    unsigned* flags = (unsigned*)((char*)d_ws + HS_BYTES);

    hipMemsetAsync(flags, 0, 4096, stream);
    hipFuncSetAttribute((const void*)lstm_wreg,
                        hipFuncAttributeMaxDynamicSharedMemorySize, SMEM_BYTES);
    lstm_wreg<<<256, 256, SMEM_BYTES, stream>>>(
        xg, hinit, cinit, W_ih, W_hh, b_ih, b_hh, attn_w, attn_b,
        W1, b1, W2, b2, W3, b3, W4, b4,
        (float*)d_out, hs, flags);
}